// Round 9
// baseline (226.882 us; speedup 1.0000x reference)
//
#include <hip/hip_runtime.h>
#include <hip/hip_bf16.h>

#define BN    4
#define NN    2048
#define INF   128
#define HH    8
#define HD    16
#define ALPHA 0.2f
#define DECAY 0.1f

// exp2 folding constants: w2 = log2e * exp(-DECAY*(ct - t)) computed as
// exp2(fma(DECAY*log2e, t, -DECAY*log2e*ct + log2(log2e)))
#define DLOG2E 0.14426950408889634f   // DECAY * log2(e)
#define LLOG2E 0.5287663729448977f    // log2(log2(e))

typedef __attribute__((ext_vector_type(8))) short short8;
typedef __attribute__((ext_vector_type(4))) float float4v;
typedef __attribute__((ext_vector_type(2))) float f32x2;

// v_cvt_pk_bf16_f32: 2 f32 -> packed 2x bf16 (RNE), single HW op.
// (Proven correct on this toolchain in rounds 3/6/8 PASS.)
__device__ __forceinline__ unsigned cvt_pk_bf16(float lo, float hi) {
    unsigned r;
    asm("v_cvt_pk_bf16_f32 %0, %1, %2" : "=v"(r) : "v"(lo), "v"(hi));
    return r;
}

// Barrier that drains ONLY LDS ops (lgkmcnt), not global loads (vmcnt).
// __syncthreads() makes hipcc emit s_waitcnt vmcnt(0) lgkmcnt(0) before
// s_barrier, force-draining the cross-round adj/tm prefetch at every round
// boundary -> all 8 waves stall together. LDS producer->consumer ordering
// (tws double buffer) only needs lgkmcnt(0). Global loads in flight keep
// their compiler-auto vmcnt waits at their uses. No global stores in loop.
__device__ __forceinline__ void block_sync_lds() {
    asm volatile("s_waitcnt lgkmcnt(0)" ::: "memory");
    __builtin_amdgcn_s_barrier();
}

// ---------------- Kernel 1: fused [max over tm] + [proj hf/es/ed] ----------
// blocks 0..1023: grid-stride max reduction (HBM-bound).
// blocks 1024..5119: projection, 2 nodes per block (latency-bound; overlaps).
// hf is written in MFMA-B-fragment-major layout: for lane (q,im) of a wave,
// hf[((b*8+h)*64 + J)*512 + lane*8 + k] = h[b][h][j = J*32 + q*8 + k][d = im]
// so k_attn's hv load is lane-consecutive (1KB coalesced per wave).
__launch_bounds__(256, 8)
__global__ void k_setup(const float* __restrict__ x,
                        const float* __restrict__ W,
                        const float* __restrict__ a,
                        const float* __restrict__ tm,
                        unsigned* __restrict__ ct,
                        __hip_bfloat16* __restrict__ hf,
                        float* __restrict__ es, float* __restrict__ ed) {
    if (blockIdx.x < 1024) {
        // ---- role A: ct = max(tm), values >= 0 so u32-compare == f32-compare
        const uint4* p = (const uint4*)tm;
        const int nvec = BN * NN * NN / 4;  // 4,194,304
        int idx = blockIdx.x * 256 + threadIdx.x;
        const int stride = 1024 * 256;
        unsigned m = 0u;
        for (int i = idx; i < nvec; i += stride) {
            uint4 v = p[i];
            m = max(m, v.x); m = max(m, v.y); m = max(m, v.z); m = max(m, v.w);
        }
        float fm = __uint_as_float(m);
        #pragma unroll
        for (int o = 32; o >= 1; o >>= 1) fm = fmaxf(fm, __shfl_xor(fm, o));
        __shared__ float sm[4];
        if ((threadIdx.x & 63) == 0) sm[threadIdx.x >> 6] = fm;
        __syncthreads();
        if (threadIdx.x == 0) {
            float mm = fmaxf(fmaxf(sm[0], sm[1]), fmaxf(sm[2], sm[3]));
            atomicMax(ct, __float_as_uint(mm));
        }
    } else {
        // ---- role B: h = x W ; hf (fragment-major bf16) ; es ; ed
        int bid = blockIdx.x - 1024;          // 0..4095
        int sub = threadIdx.x >> 7;           // which of 2 nodes
        int tt  = threadIdx.x & 127;
        int nn  = bid * 2 + sub;              // global node 0..8191 (= b*NN+n)
        __shared__ float xs[2][INF];
        xs[sub][tt] = x[(size_t)nn * INF + tt];
        __syncthreads();
        int h = tt >> 4, d = tt & 15;
        const float* Wp = W + (h * INF) * HD + d;
        float acc = 0.f;
        #pragma unroll 16
        for (int i = 0; i < INF; i++) acc += xs[sub][i] * Wp[i * HD];
        int b = nn >> 11, n = nn & 2047;
        // fragment-major store: J = j-block of 32, lane = q*16 + d, k = j&7
        {
            int J  = n >> 5;
            int q2 = (n >> 3) & 3;
            int k  = n & 7;
            hf[((size_t)(b * HH + h) * 64 + J) * 512 + (q2 * 16 + d) * 8 + k]
                = __float2bfloat16(acc);
        }
        float s  = acc * a[h * 2 * HD + d];
        float dd = acc * a[h * 2 * HD + HD + d];
        #pragma unroll
        for (int o = 8; o >= 1; o >>= 1) { s += __shfl_xor(s, o); dd += __shfl_xor(dd, o); }
        if (d == 0) {
            es[(b * HH + h) * NN + n] = s;
            ed[(b * HH + h) * NN + n] = dd;
        }
    }
}

// ---------------- Kernel 2: fused scores + partial softmax + PV (MFMA) -----
// grid: B * 2(j-half) * 128(i-tile) = 1024 blocks -> 4 blocks/CU, 32 waves/CU.
// block: 512 thr = 8 waves, wave = head. Per 128-j round the block stages the
// head-independent masked w2 = log2e*exp(-d*(ct-t)) into a DOUBLE-BUFFERED
// single LDS plane. Round boundary uses lgkmcnt-only barriers so the r+2
// adj/tm prefetch stays in flight ACROSS the barrier (no vmcnt(0) drain).
// Inner loop: packed-pair f32 + ocml exp2f + v_cvt_pk_bf16_f32 (r8 PASS body).
__launch_bounds__(512, 8)
__global__ void k_attn(const int* __restrict__ adj,
                       const float* __restrict__ tm,
                       const __hip_bfloat16* __restrict__ hf,
                       const float* __restrict__ es, const float* __restrict__ ed,
                       const unsigned* __restrict__ ctp,
                       float* __restrict__ pacc, float* __restrict__ pl) {
    int t    = threadIdx.x;
    int w    = t >> 6;          // head
    int lane = t & 63;
    int q    = lane >> 4;       // quad 0..3
    int im   = lane & 15;       // i within tile / d for B-frag
    int bx   = blockIdx.x;
    int b    = bx >> 8;
    int half = (bx >> 7) & 1;
    int i0   = (bx & 127) << 4;
    int i    = i0 + im;
    int jb   = half << 10;      // j-half base: 0 or 1024
    const int R = 8;            // 8 rounds x 128 j = 1024 j

    __shared__ float tws[2][16][132];   // double buffer; stride 132 (16B align)

    float ctv = __uint_as_float(*ctp);
    float c0  = fmaf(-DLOG2E, ctv, LLOG2E);   // -D*log2e*ct + log2(log2e)
    float es_i = es[(b * HH + w) * NN + i];
    f32x2 es2 = {es_i, es_i};
    f32x2 al2 = {ALPHA, ALPHA};

    const float* ed_p = ed + (size_t)(b * HH + w) * NN + jb + q * 8;
    // fragment-major h: base for this (b,w) + this lane's 8-element chunk
    const __hip_bfloat16* hf_p = hf + (size_t)(b * HH + w) * 32768 + lane * 8;
    int Jb = (jb >> 5);         // 0 or 32

    // staging map: 512 threads x 4 elements = 16 rows x 128 cols
    int srow = t >> 5;            // 0..15
    int scol = (t & 31) << 2;     // 0,4,...,124
    const int*   adj_s = adj + ((size_t)(b * NN + i0 + srow)) * NN + jb + scol;
    const float* tm_s  = tm  + ((size_t)(b * NN + i0 + srow)) * NN + jb + scol;

    float4v acc = {0.f, 0.f, 0.f, 0.f};
    f32x2 lacc = {0.f, 0.f};

    // prologue: stage round 0, prefetch round 1
    int4   pa = *(const int4*)(adj_s);
    float4 pt = *(const float4*)(tm_s);
    {
        float w0 = (pa.x != 0) ? exp2f(fmaf(DLOG2E, pt.x, c0)) : 0.f;
        float w1 = (pa.y != 0) ? exp2f(fmaf(DLOG2E, pt.y, c0)) : 0.f;
        float w2 = (pa.z != 0) ? exp2f(fmaf(DLOG2E, pt.z, c0)) : 0.f;
        float w3 = (pa.w != 0) ? exp2f(fmaf(DLOG2E, pt.w, c0)) : 0.f;
        *(float4*)&tws[0][srow][scol] = make_float4(w0, w1, w2, w3);
    }
    pa = *(const int4*)(adj_s + 128);
    pt = *(const float4*)(tm_s + 128);
    block_sync_lds();

    for (int r = 0; r < R; r++) {
        int cur = r & 1;

        // issue round r+2's prefetch FIRST (max latency cover; survives the
        // barrier because block_sync_lds does not drain vmcnt)
        int4   npa;
        float4 npt;
        if (r + 2 < R) {
            npa = *(const int4*)(adj_s + (r + 2) * 128);
            npt = *(const float4*)(tm_s + (r + 2) * 128);
        }

        // stage round r+1 into the other buffer (consumes pa/pt)
        if (r + 1 < R) {
            float w0 = (pa.x != 0) ? exp2f(fmaf(DLOG2E, pt.x, c0)) : 0.f;
            float w1 = (pa.y != 0) ? exp2f(fmaf(DLOG2E, pt.y, c0)) : 0.f;
            float w2 = (pa.z != 0) ? exp2f(fmaf(DLOG2E, pt.z, c0)) : 0.f;
            float w3 = (pa.w != 0) ? exp2f(fmaf(DLOG2E, pt.w, c0)) : 0.f;
            *(float4*)&tws[cur ^ 1][srow][scol] = make_float4(w0, w1, w2, w3);
        }
        if (r + 2 < R) { pa = npa; pt = npt; }

        // consume round r: packed-pair softmax math feeding MFMA A-fragments
        #pragma unroll
        for (int c4 = 0; c4 < 4; c4++) {
            int jl = c4 * 32 + q * 8;
            int jglob = r * 128 + c4 * 32;

            float4 w01 = *(const float4*)&tws[cur][im][jl];
            float4 w23 = *(const float4*)&tws[cur][im][jl + 4];
            float4 e0 = *(const float4*)(ed_p + jglob);
            float4 e1 = *(const float4*)(ed_p + jglob + 4);
            uint4  hv = *(const uint4*)(hf_p + (size_t)(Jb + r * 4 + c4) * 512);

            union { unsigned u[4]; short8 v; } af;

            auto do_pair = [&](float elo, float ehi, float wlo, float whi) -> unsigned {
                f32x2 e  = {elo, ehi};
                f32x2 wv = {wlo, whi};
                f32x2 s0 = es2 + e;                                   // v_pk_add
                f32x2 sc = __builtin_elementwise_max(s0, s0 * al2);   // v_pk_mul+max
                f32x2 uu = sc * wv;                                   // v_pk_mul
                float p0 = exp2f(uu.x);
                float p1 = exp2f(uu.y);
                p0 = (wlo > 0.f) ? p0 : 0.f;                          // masked -> 0
                p1 = (whi > 0.f) ? p1 : 0.f;
                f32x2 pv = {p0, p1};
                lacc += pv;                                           // v_pk_add
                return cvt_pk_bf16(p0, p1);
            };
            af.u[0] = do_pair(e0.x, e0.y, w01.x, w01.y);
            af.u[1] = do_pair(e0.z, e0.w, w01.z, w01.w);
            af.u[2] = do_pair(e1.x, e1.y, w23.x, w23.y);
            af.u[3] = do_pair(e1.z, e1.w, w23.z, w23.w);

            union { uint4 uu4; short8 v; } bf;
            bf.uu4 = hv;
            acc = __builtin_amdgcn_mfma_f32_16x16x32_bf16(af.v, bf.v, acc, 0, 0, 0);
        }
        block_sync_lds();
    }

    // partial row-sum l(i): lanes {i, i+16, i+32, i+48} hold quad partials
    float lsum = lacc.x + lacc.y;
    lsum += __shfl_xor(lsum, 16);
    lsum += __shfl_xor(lsum, 32);

    // dump partials: pacc[((bx*8+w)*16+row)*16+col], pl[bx*128+w*16+row]
    float* pb = pacc + (((size_t)bx * 8 + w) * 16) * 16;
    #pragma unroll
    for (int r = 0; r < 4; r++) {
        int row = q * 4 + r;
        pb[row * 16 + im] = acc[r];   // D layout: col=lane&15, row=q*4+reg
    }
    if (q == 0) pl[(size_t)bx * 128 + w * 16 + im] = lsum;
}

// ---------------- Kernel 3: combine j-halves + normalize + ELU -------------
__launch_bounds__(256, 8)
__global__ void k_fin(const float* __restrict__ pacc, const float* __restrict__ pl,
                      float* __restrict__ out) {
    int o = blockIdx.x * 256 + threadIdx.x;   // B*N*H*HD = 1,048,576
    int b   = o >> 18;
    int rem = o & 262143;
    int i   = rem >> 7;
    int hd  = rem & 127;
    int h   = hd >> 4;
    int d   = hd & 15;
    int it  = i >> 4;
    int row = i & 15;
    int blk0 = (b * 2 + 0) * 128 + it;
    int blk1 = blk0 + 128;
    float a0 = pacc[(((size_t)blk0 * 8 + h) * 16 + row) * 16 + d];
    float a1 = pacc[(((size_t)blk1 * 8 + h) * 16 + row) * 16 + d];
    float l  = pl[(size_t)blk0 * 128 + h * 16 + row]
             + pl[(size_t)blk1 * 128 + h * 16 + row];
    float v = (a0 + a1) / l;
    v = (v > 0.f) ? v : expm1f(v);   // ELU
    out[o] = v;
}

extern "C" void kernel_launch(void* const* d_in, const int* in_sizes, int n_in,
                              void* d_out, int out_size, void* d_ws, size_t ws_size,
                              hipStream_t stream) {
    const float* x   = (const float*)d_in[0];  // node_features fp32
    const int*   adj = (const int*)d_in[1];    // adjacency int32
    const float* tm  = (const float*)d_in[2];  // time_matrix fp32
    const float* W   = (const float*)d_in[3];  // W fp32
    const float* a   = (const float*)d_in[4];  // a fp32
    float* out = (float*)d_out;                // fp32 output

    float* wsf = (float*)d_ws;
    unsigned* ct = (unsigned*)wsf;                           // 1 word
    float* es = wsf + 64;                                    // 65,536
    float* ed = es + BN * HH * NN;                           // 65,536
    __hip_bfloat16* hf = (__hip_bfloat16*)(ed + BN * HH * NN);   // 1,048,576 bf16
    float* pacc = (float*)(hf + BN * HH * HD * NN);          // 2,097,152
    float* pl   = pacc + 1024 * 2048;                        // 131,072
    // total ws use ~= 11.5 MB

    hipMemsetAsync(d_ws, 0, 4, stream);                      // ct = 0.0f (t >= 0)
    k_setup<<<1024 + 4096, 256, 0, stream>>>(x, W, a, tm, ct, hf, es, ed);
    k_attn <<<BN * 2 * (NN / 16), 512, 0, stream>>>(adj, tm, hf, es, ed, ct, pacc, pl);
    k_fin  <<<(BN * NN * HH * HD) / 256, 256, 0, stream>>>(pacc, pl, out);
}

// Round 10
// 217.561 us; speedup vs baseline: 1.0428x; 1.0428x over previous
//
#include <hip/hip_runtime.h>
#include <hip/hip_bf16.h>

#define BN    4
#define NN    2048
#define INF   128
#define HH    8
#define HD    16
#define ALPHA 0.2f
#define DECAY 0.1f

typedef __attribute__((ext_vector_type(8))) short short8;
typedef __attribute__((ext_vector_type(4))) float float4v;
typedef __attribute__((ext_vector_type(2))) float f32x2;

// v_cvt_pk_bf16_f32: 2 f32 -> packed 2x bf16 (RNE), single HW op.
// (Proven correct on this toolchain in rounds 3/6/8 PASS.)
__device__ __forceinline__ unsigned cvt_pk_bf16(float lo, float hi) {
    unsigned r;
    asm("v_cvt_pk_bf16_f32 %0, %1, %2" : "=v"(r) : "v"(lo), "v"(hi));
    return r;
}

// ---------------- Kernel 1: fused [max over tm] + [proj hf/es/ed] ----------
// blocks 0..1023: grid-stride max reduction (HBM-bound).
// blocks 1024..5119: projection, 2 nodes per block (latency-bound; overlaps).
// hf is written in MFMA-B-fragment-major layout: for lane (q,im) of a wave,
// hf[((b*8+h)*64 + J)*512 + lane*8 + k] = h[b][h][j = J*32 + q*8 + k][d = im]
// so k_attn's hv load is lane-consecutive (1KB coalesced per wave).
__launch_bounds__(256, 8)
__global__ void k_setup(const float* __restrict__ x,
                        const float* __restrict__ W,
                        const float* __restrict__ a,
                        const float* __restrict__ tm,
                        unsigned* __restrict__ ct,
                        __hip_bfloat16* __restrict__ hf,
                        float* __restrict__ es, float* __restrict__ ed) {
    if (blockIdx.x < 1024) {
        // ---- role A: ct = max(tm), values >= 0 so u32-compare == f32-compare
        const uint4* p = (const uint4*)tm;
        const int nvec = BN * NN * NN / 4;  // 4,194,304
        int idx = blockIdx.x * 256 + threadIdx.x;
        const int stride = 1024 * 256;
        unsigned m = 0u;
        for (int i = idx; i < nvec; i += stride) {
            uint4 v = p[i];
            m = max(m, v.x); m = max(m, v.y); m = max(m, v.z); m = max(m, v.w);
        }
        float fm = __uint_as_float(m);
        #pragma unroll
        for (int o = 32; o >= 1; o >>= 1) fm = fmaxf(fm, __shfl_xor(fm, o));
        __shared__ float sm[4];
        if ((threadIdx.x & 63) == 0) sm[threadIdx.x >> 6] = fm;
        __syncthreads();
        if (threadIdx.x == 0) {
            float mm = fmaxf(fmaxf(sm[0], sm[1]), fmaxf(sm[2], sm[3]));
            atomicMax(ct, __float_as_uint(mm));
        }
    } else {
        // ---- role B: h = x W ; hf (fragment-major bf16) ; es ; ed
        int bid = blockIdx.x - 1024;          // 0..4095
        int sub = threadIdx.x >> 7;           // which of 2 nodes
        int tt  = threadIdx.x & 127;
        int nn  = bid * 2 + sub;              // global node 0..8191 (= b*NN+n)
        __shared__ float xs[2][INF];
        xs[sub][tt] = x[(size_t)nn * INF + tt];
        __syncthreads();
        int h = tt >> 4, d = tt & 15;
        const float* Wp = W + (h * INF) * HD + d;
        float acc = 0.f;
        #pragma unroll 16
        for (int i = 0; i < INF; i++) acc += xs[sub][i] * Wp[i * HD];
        int b = nn >> 11, n = nn & 2047;
        // fragment-major store: J = j-block of 32, lane = q*16 + d, k = j&7
        {
            int J  = n >> 5;
            int q2 = (n >> 3) & 3;
            int k  = n & 7;
            hf[((size_t)(b * HH + h) * 64 + J) * 512 + (q2 * 16 + d) * 8 + k]
                = __float2bfloat16(acc);
        }
        float s  = acc * a[h * 2 * HD + d];
        float dd = acc * a[h * 2 * HD + HD + d];
        #pragma unroll
        for (int o = 8; o >= 1; o >>= 1) { s += __shfl_xor(s, o); dd += __shfl_xor(dd, o); }
        if (d == 0) {
            es[(b * HH + h) * NN + n] = s;
            ed[(b * HH + h) * NN + n] = dd;
        }
    }
}

// ---------------- Kernel 2: fused scores + partial softmax + PV (MFMA) -----
// grid: B * 2(j-half) * 128(i-tile) = 1024 blocks -> 4 blocks/CU, 32 waves/CU.
// block: 512 thr = 8 waves, wave = head. Per 128-j round the block stages the
// head-independent masked tw = exp(-DECAY*(ct-t)) into a DOUBLE-BUFFERED
// single LDS plane (one barrier per round, r8 PASS structure). All exps are
// __expf (native v_exp_f32, ~2 VALU) instead of ocml exp2f (~15-20 VALU with
// denormal fixup): 151M calls made the wrapper ~60% of all VALU issue.
__launch_bounds__(512, 8)
__global__ void k_attn(const int* __restrict__ adj,
                       const float* __restrict__ tm,
                       const __hip_bfloat16* __restrict__ hf,
                       const float* __restrict__ es, const float* __restrict__ ed,
                       const unsigned* __restrict__ ctp,
                       float* __restrict__ pacc, float* __restrict__ pl) {
    int t    = threadIdx.x;
    int w    = t >> 6;          // head
    int lane = t & 63;
    int q    = lane >> 4;       // quad 0..3
    int im   = lane & 15;       // i within tile / d for B-frag
    int bx   = blockIdx.x;
    int b    = bx >> 8;
    int half = (bx >> 7) & 1;
    int i0   = (bx & 127) << 4;
    int i    = i0 + im;
    int jb   = half << 10;      // j-half base: 0 or 1024
    const int R = 8;            // 8 rounds x 128 j = 1024 j

    __shared__ float tws[2][16][132];   // double buffer; stride 132 (16B align)

    float ctv = __uint_as_float(*ctp);
    float c0  = -DECAY * ctv;                 // tw = exp(DECAY*t + c0)
    float es_i = es[(b * HH + w) * NN + i];
    f32x2 es2 = {es_i, es_i};
    f32x2 al2 = {ALPHA, ALPHA};

    const float* ed_p = ed + (size_t)(b * HH + w) * NN + jb + q * 8;
    // fragment-major h: base for this (b,w) + this lane's 8-element chunk
    const __hip_bfloat16* hf_p = hf + (size_t)(b * HH + w) * 32768 + lane * 8;
    int Jb = (jb >> 5);         // 0 or 32

    // staging map: 512 threads x 4 elements = 16 rows x 128 cols
    int srow = t >> 5;            // 0..15
    int scol = (t & 31) << 2;     // 0,4,...,124
    const int*   adj_s = adj + ((size_t)(b * NN + i0 + srow)) * NN + jb + scol;
    const float* tm_s  = tm  + ((size_t)(b * NN + i0 + srow)) * NN + jb + scol;

    float4v acc = {0.f, 0.f, 0.f, 0.f};
    f32x2 lacc = {0.f, 0.f};

    // prologue: stage round 0, prefetch round 1
    int4   pa = *(const int4*)(adj_s);
    float4 pt = *(const float4*)(tm_s);
    {
        float w0 = (pa.x != 0) ? __expf(fmaf(DECAY, pt.x, c0)) : 0.f;
        float w1 = (pa.y != 0) ? __expf(fmaf(DECAY, pt.y, c0)) : 0.f;
        float w2 = (pa.z != 0) ? __expf(fmaf(DECAY, pt.z, c0)) : 0.f;
        float w3 = (pa.w != 0) ? __expf(fmaf(DECAY, pt.w, c0)) : 0.f;
        *(float4*)&tws[0][srow][scol] = make_float4(w0, w1, w2, w3);
    }
    pa = *(const int4*)(adj_s + 128);
    pt = *(const float4*)(tm_s + 128);
    __syncthreads();

    for (int r = 0; r < R; r++) {
        int cur = r & 1;
        // stage round r+1 into the other buffer; prefetch round r+2
        if (r + 1 < R) {
            float w0 = (pa.x != 0) ? __expf(fmaf(DECAY, pt.x, c0)) : 0.f;
            float w1 = (pa.y != 0) ? __expf(fmaf(DECAY, pt.y, c0)) : 0.f;
            float w2 = (pa.z != 0) ? __expf(fmaf(DECAY, pt.z, c0)) : 0.f;
            float w3 = (pa.w != 0) ? __expf(fmaf(DECAY, pt.w, c0)) : 0.f;
            *(float4*)&tws[cur ^ 1][srow][scol] = make_float4(w0, w1, w2, w3);
            if (r + 2 < R) {
                pa = *(const int4*)(adj_s + (r + 2) * 128);
                pt = *(const float4*)(tm_s + (r + 2) * 128);
            }
        }
        // consume round r: packed-pair softmax math feeding MFMA A-fragments
        #pragma unroll
        for (int c4 = 0; c4 < 4; c4++) {
            int jl = c4 * 32 + q * 8;
            int jglob = r * 128 + c4 * 32;

            float4 w01 = *(const float4*)&tws[cur][im][jl];
            float4 w23 = *(const float4*)&tws[cur][im][jl + 4];
            float4 e0 = *(const float4*)(ed_p + jglob);
            float4 e1 = *(const float4*)(ed_p + jglob + 4);
            uint4  hv = *(const uint4*)(hf_p + (size_t)(Jb + r * 4 + c4) * 512);

            union { unsigned u[4]; short8 v; } af;

            auto do_pair = [&](float elo, float ehi, float wlo, float whi) -> unsigned {
                f32x2 e  = {elo, ehi};
                f32x2 wv = {wlo, whi};
                f32x2 s0 = es2 + e;                                   // v_pk_add
                f32x2 sc = __builtin_elementwise_max(s0, s0 * al2);   // v_pk_mul+max
                f32x2 uu = sc * wv;                                   // v_pk_mul
                float p0 = __expf(uu.x);                              // v_mul+v_exp
                float p1 = __expf(uu.y);
                p0 = (wlo > 0.f) ? p0 : 0.f;                          // masked -> 0
                p1 = (whi > 0.f) ? p1 : 0.f;
                f32x2 pv = {p0, p1};
                lacc += pv;                                           // v_pk_add
                return cvt_pk_bf16(p0, p1);
            };
            af.u[0] = do_pair(e0.x, e0.y, w01.x, w01.y);
            af.u[1] = do_pair(e0.z, e0.w, w01.z, w01.w);
            af.u[2] = do_pair(e1.x, e1.y, w23.x, w23.y);
            af.u[3] = do_pair(e1.z, e1.w, w23.z, w23.w);

            union { uint4 uu4; short8 v; } bf;
            bf.uu4 = hv;
            acc = __builtin_amdgcn_mfma_f32_16x16x32_bf16(af.v, bf.v, acc, 0, 0, 0);
        }
        __syncthreads();
    }

    // partial row-sum l(i): lanes {i, i+16, i+32, i+48} hold quad partials
    float lsum = lacc.x + lacc.y;
    lsum += __shfl_xor(lsum, 16);
    lsum += __shfl_xor(lsum, 32);

    // dump partials: pacc[((bx*8+w)*16+row)*16+col], pl[bx*128+w*16+row]
    float* pb = pacc + (((size_t)bx * 8 + w) * 16) * 16;
    #pragma unroll
    for (int r = 0; r < 4; r++) {
        int row = q * 4 + r;
        pb[row * 16 + im] = acc[r];   // D layout: col=lane&15, row=q*4+reg
    }
    if (q == 0) pl[(size_t)bx * 128 + w * 16 + im] = lsum;
}

// ---------------- Kernel 3: combine j-halves + normalize + ELU -------------
__launch_bounds__(256, 8)
__global__ void k_fin(const float* __restrict__ pacc, const float* __restrict__ pl,
                      float* __restrict__ out) {
    int o = blockIdx.x * 256 + threadIdx.x;   // B*N*H*HD = 1,048,576
    int b   = o >> 18;
    int rem = o & 262143;
    int i   = rem >> 7;
    int hd  = rem & 127;
    int h   = hd >> 4;
    int d   = hd & 15;
    int it  = i >> 4;
    int row = i & 15;
    int blk0 = (b * 2 + 0) * 128 + it;
    int blk1 = blk0 + 128;
    float a0 = pacc[(((size_t)blk0 * 8 + h) * 16 + row) * 16 + d];
    float a1 = pacc[(((size_t)blk1 * 8 + h) * 16 + row) * 16 + d];
    float l  = pl[(size_t)blk0 * 128 + h * 16 + row]
             + pl[(size_t)blk1 * 128 + h * 16 + row];
    float v = (a0 + a1) / l;
    v = (v > 0.f) ? v : expm1f(v);   // ELU
    out[o] = v;
}

extern "C" void kernel_launch(void* const* d_in, const int* in_sizes, int n_in,
                              void* d_out, int out_size, void* d_ws, size_t ws_size,
                              hipStream_t stream) {
    const float* x   = (const float*)d_in[0];  // node_features fp32
    const int*   adj = (const int*)d_in[1];    // adjacency int32
    const float* tm  = (const float*)d_in[2];  // time_matrix fp32
    const float* W   = (const float*)d_in[3];  // W fp32
    const float* a   = (const float*)d_in[4];  // a fp32
    float* out = (float*)d_out;                // fp32 output

    float* wsf = (float*)d_ws;
    unsigned* ct = (unsigned*)wsf;                           // 1 word
    float* es = wsf + 64;                                    // 65,536
    float* ed = es + BN * HH * NN;                           // 65,536
    __hip_bfloat16* hf = (__hip_bfloat16*)(ed + BN * HH * NN);   // 1,048,576 bf16
    float* pacc = (float*)(hf + BN * HH * HD * NN);          // 2,097,152
    float* pl   = pacc + 1024 * 2048;                        // 131,072
    // total ws use ~= 11.5 MB

    hipMemsetAsync(d_ws, 0, 4, stream);                      // ct = 0.0f (t >= 0)
    k_setup<<<1024 + 4096, 256, 0, stream>>>(x, W, a, tm, ct, hf, es, ed);
    k_attn <<<BN * 2 * (NN / 16), 512, 0, stream>>>(adj, tm, hf, es, ed, ct, pacc, pl);
    k_fin  <<<(BN * NN * HH * HD) / 256, 256, 0, stream>>>(pacc, pl, out);
}

// Round 11
// 215.231 us; speedup vs baseline: 1.0541x; 1.0108x over previous
//
#include <hip/hip_runtime.h>
#include <hip/hip_bf16.h>

#define BN    4
#define NN    2048
#define INF   128
#define HH    8
#define HD    16
#define ALPHA 0.2f
#define DECAY 0.1f

typedef __attribute__((ext_vector_type(8))) short short8;
typedef __attribute__((ext_vector_type(4))) float float4v;
typedef __attribute__((ext_vector_type(2))) float f32x2;

// v_cvt_pk_bf16_f32: 2 f32 -> packed 2x bf16 (RNE), single HW op.
// (Proven correct on this toolchain in rounds 3/6/8/10 PASS.)
__device__ __forceinline__ unsigned cvt_pk_bf16(float lo, float hi) {
    unsigned r;
    asm("v_cvt_pk_bf16_f32 %0, %1, %2" : "=v"(r) : "v"(lo), "v"(hi));
    return r;
}

// ---------------- Kernel 1: fused [max over tm] + [proj hf/es/ed] ----------
// blocks 0..1023: grid-stride max reduction (HBM-bound).
// blocks 1024..5119: projection, 2 nodes per block (latency-bound; overlaps).
// hf is written in MFMA-B-fragment-major layout: for lane (q,im) of a wave,
// hf[((b*8+h)*64 + J)*512 + lane*8 + k] = h[b][h][j = J*32 + q*8 + k][d = im]
// so k_attn's hv load is lane-consecutive (1KB coalesced per wave).
__launch_bounds__(256, 8)
__global__ void k_setup(const float* __restrict__ x,
                        const float* __restrict__ W,
                        const float* __restrict__ a,
                        const float* __restrict__ tm,
                        unsigned* __restrict__ ct,
                        __hip_bfloat16* __restrict__ hf,
                        float* __restrict__ es, float* __restrict__ ed) {
    if (blockIdx.x < 1024) {
        // ---- role A: ct = max(tm), values >= 0 so u32-compare == f32-compare
        const uint4* p = (const uint4*)tm;
        const int nvec = BN * NN * NN / 4;  // 4,194,304
        int idx = blockIdx.x * 256 + threadIdx.x;
        const int stride = 1024 * 256;
        unsigned m = 0u;
        for (int i = idx; i < nvec; i += stride) {
            uint4 v = p[i];
            m = max(m, v.x); m = max(m, v.y); m = max(m, v.z); m = max(m, v.w);
        }
        float fm = __uint_as_float(m);
        #pragma unroll
        for (int o = 32; o >= 1; o >>= 1) fm = fmaxf(fm, __shfl_xor(fm, o));
        __shared__ float sm[4];
        if ((threadIdx.x & 63) == 0) sm[threadIdx.x >> 6] = fm;
        __syncthreads();
        if (threadIdx.x == 0) {
            float mm = fmaxf(fmaxf(sm[0], sm[1]), fmaxf(sm[2], sm[3]));
            atomicMax(ct, __float_as_uint(mm));
        }
    } else {
        // ---- role B: h = x W ; hf (fragment-major bf16) ; es ; ed
        int bid = blockIdx.x - 1024;          // 0..4095
        int sub = threadIdx.x >> 7;           // which of 2 nodes
        int tt  = threadIdx.x & 127;
        int nn  = bid * 2 + sub;              // global node 0..8191 (= b*NN+n)
        __shared__ float xs[2][INF];
        xs[sub][tt] = x[(size_t)nn * INF + tt];
        __syncthreads();
        int h = tt >> 4, d = tt & 15;
        const float* Wp = W + (h * INF) * HD + d;
        float acc = 0.f;
        #pragma unroll 16
        for (int i = 0; i < INF; i++) acc += xs[sub][i] * Wp[i * HD];
        int b = nn >> 11, n = nn & 2047;
        // fragment-major store: J = j-block of 32, lane = q*16 + d, k = j&7
        {
            int J  = n >> 5;
            int q2 = (n >> 3) & 3;
            int k  = n & 7;
            hf[((size_t)(b * HH + h) * 64 + J) * 512 + (q2 * 16 + d) * 8 + k]
                = __float2bfloat16(acc);
        }
        float s  = acc * a[h * 2 * HD + d];
        float dd = acc * a[h * 2 * HD + HD + d];
        #pragma unroll
        for (int o = 8; o >= 1; o >>= 1) { s += __shfl_xor(s, o); dd += __shfl_xor(dd, o); }
        if (d == 0) {
            es[(b * HH + h) * NN + n] = s;
            ed[(b * HH + h) * NN + n] = dd;
        }
    }
}

// ---------------- Kernel 2: fused scores + partial softmax + PV (MFMA) -----
// grid: B * 2(j-half) * 128(i-tile) = 1024 blocks -> 4 blocks/CU, 32 waves/CU.
// block: 512 thr = 8 waves, wave = head. Per 128-j round the block stages the
// head-independent masked tw = exp(-DECAY*(ct-t)) into a DOUBLE-BUFFERED
// single LDS plane (r10 PASS structure). All exps are __expf (native
// v_exp_f32). New this round: (a) row-sums l(i) via a second MFMA against an
// all-ones B fragment (removes the lacc pk_add chain + epilogue shuffles;
// matrix pipe is ~2.6% utilized, free); (b) the r+2 adj/tm prefetch is issued
// at round top and PINNED there with sched_barrier(0) so the compiler cannot
// sink it to its use (round-7 failure mode) -> ~600cy of flight before the
// barrier drain.
__launch_bounds__(512, 8)
__global__ void k_attn(const int* __restrict__ adj,
                       const float* __restrict__ tm,
                       const __hip_bfloat16* __restrict__ hf,
                       const float* __restrict__ es, const float* __restrict__ ed,
                       const unsigned* __restrict__ ctp,
                       float* __restrict__ pacc, float* __restrict__ pl) {
    int t    = threadIdx.x;
    int w    = t >> 6;          // head
    int lane = t & 63;
    int q    = lane >> 4;       // quad 0..3
    int im   = lane & 15;       // i within tile / d for B-frag
    int bx   = blockIdx.x;
    int b    = bx >> 8;
    int half = (bx >> 7) & 1;
    int i0   = (bx & 127) << 4;
    int i    = i0 + im;
    int jb   = half << 10;      // j-half base: 0 or 1024
    const int R = 8;            // 8 rounds x 128 j = 1024 j

    __shared__ float tws[2][16][132];   // double buffer; stride 132 (16B align)

    float ctv = __uint_as_float(*ctp);
    float c0  = -DECAY * ctv;                 // tw = exp(DECAY*t + c0)
    float es_i = es[(b * HH + w) * NN + i];
    f32x2 es2 = {es_i, es_i};
    f32x2 al2 = {ALPHA, ALPHA};

    const float* ed_p = ed + (size_t)(b * HH + w) * NN + jb + q * 8;
    // fragment-major h: base for this (b,w) + this lane's 8-element chunk
    const __hip_bfloat16* hf_p = hf + (size_t)(b * HH + w) * 32768 + lane * 8;
    int Jb = (jb >> 5);         // 0 or 32

    // staging map: 512 threads x 4 elements = 16 rows x 128 cols
    int srow = t >> 5;            // 0..15
    int scol = (t & 31) << 2;     // 0,4,...,124
    const int*   adj_s = adj + ((size_t)(b * NN + i0 + srow)) * NN + jb + scol;
    const float* tm_s  = tm  + ((size_t)(b * NN + i0 + srow)) * NN + jb + scol;

    float4v acc  = {0.f, 0.f, 0.f, 0.f};
    float4v accl = {0.f, 0.f, 0.f, 0.f};   // row-sum accumulator (ones-MFMA)

    // all-ones B fragment (bf16 1.0 = 0x3F80)
    union { unsigned u[4]; short8 v; } ones;
    #pragma unroll
    for (int k = 0; k < 4; k++) ones.u[k] = 0x3F803F80u;

    // prologue: stage round 0, prefetch round 1
    int4   pa = *(const int4*)(adj_s);
    float4 pt = *(const float4*)(tm_s);
    {
        float w0 = (pa.x != 0) ? __expf(fmaf(DECAY, pt.x, c0)) : 0.f;
        float w1 = (pa.y != 0) ? __expf(fmaf(DECAY, pt.y, c0)) : 0.f;
        float w2 = (pa.z != 0) ? __expf(fmaf(DECAY, pt.z, c0)) : 0.f;
        float w3 = (pa.w != 0) ? __expf(fmaf(DECAY, pt.w, c0)) : 0.f;
        *(float4*)&tws[0][srow][scol] = make_float4(w0, w1, w2, w3);
    }
    pa = *(const int4*)(adj_s + 128);
    pt = *(const float4*)(tm_s + 128);
    __syncthreads();

    for (int r = 0; r < R; r++) {
        int cur = r & 1;

        // issue round r+2's prefetch FIRST, then pin it: the scheduler may
        // not move instructions across sched_barrier(0), so these loads
        // cannot be sunk to their use next round (r7's failure mode).
        int4   npa = pa;
        float4 npt = pt;
        if (r + 2 < R) {
            npa = *(const int4*)(adj_s + (r + 2) * 128);
            npt = *(const float4*)(tm_s + (r + 2) * 128);
        }
        __builtin_amdgcn_sched_barrier(0);

        // stage round r+1 into the other buffer (consumes pa/pt)
        if (r + 1 < R) {
            float w0 = (pa.x != 0) ? __expf(fmaf(DECAY, pt.x, c0)) : 0.f;
            float w1 = (pa.y != 0) ? __expf(fmaf(DECAY, pt.y, c0)) : 0.f;
            float w2 = (pa.z != 0) ? __expf(fmaf(DECAY, pt.z, c0)) : 0.f;
            float w3 = (pa.w != 0) ? __expf(fmaf(DECAY, pt.w, c0)) : 0.f;
            *(float4*)&tws[cur ^ 1][srow][scol] = make_float4(w0, w1, w2, w3);
        }
        pa = npa; pt = npt;

        // consume round r: packed-pair softmax math feeding MFMA A-fragments
        #pragma unroll
        for (int c4 = 0; c4 < 4; c4++) {
            int jl = c4 * 32 + q * 8;
            int jglob = r * 128 + c4 * 32;

            float4 w01 = *(const float4*)&tws[cur][im][jl];
            float4 w23 = *(const float4*)&tws[cur][im][jl + 4];
            float4 e0 = *(const float4*)(ed_p + jglob);
            float4 e1 = *(const float4*)(ed_p + jglob + 4);
            uint4  hv = *(const uint4*)(hf_p + (size_t)(Jb + r * 4 + c4) * 512);

            union { unsigned u[4]; short8 v; } af;

            auto do_pair = [&](float elo, float ehi, float wlo, float whi) -> unsigned {
                f32x2 e  = {elo, ehi};
                f32x2 wv = {wlo, whi};
                f32x2 s0 = es2 + e;                                   // v_pk_add
                f32x2 sc = __builtin_elementwise_max(s0, s0 * al2);   // v_pk_mul+max
                f32x2 uu = sc * wv;                                   // v_pk_mul
                float p0 = __expf(uu.x);                              // v_mul+v_exp
                float p1 = __expf(uu.y);
                p0 = (wlo > 0.f) ? p0 : 0.f;                          // masked -> 0
                p1 = (whi > 0.f) ? p1 : 0.f;
                return cvt_pk_bf16(p0, p1);
            };
            af.u[0] = do_pair(e0.x, e0.y, w01.x, w01.y);
            af.u[1] = do_pair(e0.z, e0.w, w01.z, w01.w);
            af.u[2] = do_pair(e1.x, e1.y, w23.x, w23.y);
            af.u[3] = do_pair(e1.z, e1.w, w23.z, w23.w);

            union { uint4 uu4; short8 v; } bf;
            bf.uu4 = hv;
            acc  = __builtin_amdgcn_mfma_f32_16x16x32_bf16(af.v, bf.v,   acc,  0, 0, 0);
            accl = __builtin_amdgcn_mfma_f32_16x16x32_bf16(af.v, ones.v, accl, 0, 0, 0);
        }
        __syncthreads();
    }

    // dump partials: pacc[((bx*8+w)*16+row)*16+col], pl[bx*128+w*16+row]
    // D layout: col=lane&15, row=q*4+reg. accl[r] = l(q*4+r) at every col
    // (row-sum of P row q*4+r; B=ones is layout-invariant across cols).
    float* pb = pacc + (((size_t)bx * 8 + w) * 16) * 16;
    #pragma unroll
    for (int r = 0; r < 4; r++) {
        int row = q * 4 + r;
        pb[row * 16 + im] = acc[r];
        if (im == 0) pl[(size_t)bx * 128 + w * 16 + row] = accl[r];
    }
}

// ---------------- Kernel 3: combine j-halves + normalize + ELU -------------
__launch_bounds__(256, 8)
__global__ void k_fin(const float* __restrict__ pacc, const float* __restrict__ pl,
                      float* __restrict__ out) {
    int o = blockIdx.x * 256 + threadIdx.x;   // B*N*H*HD = 1,048,576
    int b   = o >> 18;
    int rem = o & 262143;
    int i   = rem >> 7;
    int hd  = rem & 127;
    int h   = hd >> 4;
    int d   = hd & 15;
    int it  = i >> 4;
    int row = i & 15;
    int blk0 = (b * 2 + 0) * 128 + it;
    int blk1 = blk0 + 128;
    float a0 = pacc[(((size_t)blk0 * 8 + h) * 16 + row) * 16 + d];
    float a1 = pacc[(((size_t)blk1 * 8 + h) * 16 + row) * 16 + d];
    float l  = pl[(size_t)blk0 * 128 + h * 16 + row]
             + pl[(size_t)blk1 * 128 + h * 16 + row];
    float v = (a0 + a1) / l;
    v = (v > 0.f) ? v : expm1f(v);   // ELU
    out[o] = v;
}

extern "C" void kernel_launch(void* const* d_in, const int* in_sizes, int n_in,
                              void* d_out, int out_size, void* d_ws, size_t ws_size,
                              hipStream_t stream) {
    const float* x   = (const float*)d_in[0];  // node_features fp32
    const int*   adj = (const int*)d_in[1];    // adjacency int32
    const float* tm  = (const float*)d_in[2];  // time_matrix fp32
    const float* W   = (const float*)d_in[3];  // W fp32
    const float* a   = (const float*)d_in[4];  // a fp32
    float* out = (float*)d_out;                // fp32 output

    float* wsf = (float*)d_ws;
    unsigned* ct = (unsigned*)wsf;                           // 1 word
    float* es = wsf + 64;                                    // 65,536
    float* ed = es + BN * HH * NN;                           // 65,536
    __hip_bfloat16* hf = (__hip_bfloat16*)(ed + BN * HH * NN);   // 1,048,576 bf16
    float* pacc = (float*)(hf + BN * HH * HD * NN);          // 2,097,152
    float* pl   = pacc + 1024 * 2048;                        // 131,072
    // total ws use ~= 11.5 MB

    hipMemsetAsync(d_ws, 0, 4, stream);                      // ct = 0.0f (t >= 0)
    k_setup<<<1024 + 4096, 256, 0, stream>>>(x, W, a, tm, ct, hf, es, ed);
    k_attn <<<BN * 2 * (NN / 16), 512, 0, stream>>>(adj, tm, hf, es, ed, ct, pacc, pl);
    k_fin  <<<(BN * NN * HH * HD) / 256, 256, 0, stream>>>(pacc, pl, out);
}